// Round 9
// baseline (318.554 us; speedup 1.0000x reference)
//
#include <hip/hip_runtime.h>
#include <math.h>

// ---------------------------------------------------------------------------
// GAT 3-layer forward. GEMMs bf16-MFMA (f32 acc) with global_load_lds
// double-buffered staging + fused alpha-dot epilogue (f32, atomicAdd);
// h kept in bf16 only; aggregation = 2 waves/node, single-pass unnormalized
// softmax (logits bounded ~12 << 88), producer/consumer in LDS.
// N=10000, IN=256, HID=128, HEADS=4, OUT=128, E=320000 (+N self loops).
// ---------------------------------------------------------------------------

#define NEG_SLOPE 0.2f

typedef float f32x4 __attribute__((ext_vector_type(4)));
typedef short s16x8 __attribute__((ext_vector_type(8)));

__device__ inline unsigned short f2bf(float x) {
    unsigned int u = __builtin_bit_cast(unsigned int, x);
    u = (u + 0x7fff + ((u >> 16) & 1)) >> 16;   // RNE
    return (unsigned short)u;
}
__device__ inline float bf2f(unsigned short b) {
    return __builtin_bit_cast(float, ((unsigned int)b) << 16);
}

// ---------------- CSR build (scan + fill) ----------------

__global__ __launch_bounds__(256) void k_scan(const int* __restrict__ counts, int N,
                                              int* __restrict__ row_ptr,
                                              int* __restrict__ cursor) {
    __shared__ int s[256];
    int t = threadIdx.x;
    int per = (N + 255) / 256;
    int beg = t * per;
    int local = 0;
    for (int j = 0; j < per; ++j) {
        int i = beg + j;
        if (i < N) local += counts[i];
    }
    s[t] = local;
    __syncthreads();
    for (int off = 1; off < 256; off <<= 1) {
        int v = (t >= off) ? s[t - off] : 0;
        __syncthreads();
        s[t] += v;
        __syncthreads();
    }
    int run = (t == 0) ? 0 : s[t - 1];
    for (int j = 0; j < per; ++j) {
        int i = beg + j;
        if (i < N) {
            row_ptr[i] = run;
            cursor[i] = run;
            run += counts[i];
        }
    }
    if (t == 255) row_ptr[N] = s[255];
}

__global__ void k_fill(const int* __restrict__ ei, int E, int N,
                       int* __restrict__ cursor, int* __restrict__ csr_src) {
    int e = blockIdx.x * blockDim.x + threadIdx.x;
    if (e >= E + N) return;
    int src, dst;
    if (e < E) {
        src = ei[e];
        dst = ei[(size_t)E + e];
    } else {
        src = dst = e - E;
    }
    if ((unsigned)dst >= (unsigned)N || (unsigned)src >= (unsigned)N) return;
    int slot = atomicAdd(&cursor[dst], 1);
    csr_src[slot] = src;
}

// ---------------- fused prep: edge-count | weight transpose-cast | x cast ---

__global__ __launch_bounds__(256) void k_prep(
    const int* __restrict__ ei, int E, int N, int* __restrict__ counts,
    const float* __restrict__ W0c, unsigned short* __restrict__ T0,
    const float* __restrict__ W1c, unsigned short* __restrict__ T1,
    const float* __restrict__ W2c, unsigned short* __restrict__ T2,
    const float* __restrict__ x, unsigned short* __restrict__ xo, int nx, int eb) {
    __shared__ float tile[32][33];
    int bid = blockIdx.x;
    if (bid < eb) {
        int e = bid * 256 + threadIdx.x;
        if (e >= E + N) return;
        int dst = (e < E) ? ei[(size_t)E + e] : (e - E);
        if ((unsigned)dst >= (unsigned)N) return;
        atomicAdd(&counts[dst], 1);
        return;
    }
    bid -= eb;
    if (bid < 448) {
        const float* W;
        unsigned short* T;
        int K, Nc, t;
        if (bid < 128)      { W = W0c; T = T0; K = 256; Nc = 512; t = bid; }
        else if (bid < 384) { W = W1c; T = T1; K = 512; Nc = 512; t = bid - 128; }
        else                { W = W2c; T = T2; K = 512; Nc = 128; t = bid - 384; }
        int nt = Nc / 32;
        int n0 = (t % nt) * 32, k0 = (t / nt) * 32;
        int tx = threadIdx.x % 32, ty = threadIdx.x / 32;  // 32 x 8
#pragma unroll
        for (int i = 0; i < 32; i += 8)
            tile[ty + i][tx] = W[(size_t)(k0 + ty + i) * Nc + n0 + tx];
        __syncthreads();
#pragma unroll
        for (int i = 0; i < 32; i += 8)
            T[(size_t)(n0 + ty + i) * K + k0 + tx] = f2bf(tile[tx][ty + i]);
        return;
    }
    bid -= 448;
    int i = (bid * 256 + threadIdx.x) * 4;
    if (i >= nx) return;
    if (i + 3 >= nx) {
        for (int j = i; j < nx; ++j) xo[j] = f2bf(x[j]);
        return;
    }
    float4 v = *(const float4*)(x + i);
    xo[i + 0] = f2bf(v.x);
    xo[i + 1] = f2bf(v.y);
    xo[i + 2] = f2bf(v.z);
    xo[i + 3] = f2bf(v.w);
}

// ---------------- bf16 MFMA GEMM + fused alpha-dot epilogue ----------------
// Cbf[M][N] = A[M][K](bf16) * Bt[N][K]^T(bf16).  BM=128 BN=64 BK=64, 4 waves.
// Epilogue also accumulates as_[m,h]=<C[m,:],a_src[h,:]> and ad_ likewise via
// one f32 atomicAdd per row per block (cols of a block lie in ONE head).

__global__ __launch_bounds__(256) void k_mgemm(const unsigned short* __restrict__ A,
                                               const unsigned short* __restrict__ Bt,
                                               unsigned short* __restrict__ Cbf,
                                               const float* __restrict__ a_src,
                                               const float* __restrict__ a_dst,
                                               float* __restrict__ as_,
                                               float* __restrict__ ad_,
                                               int M, int N, int K, int H) {
    constexpr int BM = 128, BN = 64, BK = 64;
    constexpr int BUF = (BM + BN) * BK * 2;      // 24576 bytes
    __shared__ char lds[2][BUF];

    int tid = threadIdx.x;
    int w = tid >> 6, l = tid & 63;
    int r = l & 15, g = l >> 4;
    int bm = blockIdx.x * BM, bn = blockIdx.y * BN;

    int row8 = l >> 3;
    int slot = l & 7;

    f32x4 acc[2][4];
#pragma unroll
    for (int i = 0; i < 2; ++i)
#pragma unroll
        for (int j = 0; j < 4; ++j) acc[i][j] = (f32x4)0.f;

    auto stage = [&](int buf, int k0) {
        char* Asl = lds[buf];
        char* Bsl = lds[buf] + BM * BK * 2;
#pragma unroll
        for (int p = 0; p < 4; ++p) {
            int base_row = p * 32 + w * 8;
            int row = base_row + row8;
            const unsigned short* gp =
                A + (size_t)(bm + row) * K + k0 + ((slot ^ (row & 7)) * 8);
            __builtin_amdgcn_global_load_lds(
                (const __attribute__((address_space(1))) void*)gp,
                (__attribute__((address_space(3))) void*)(Asl + base_row * (BK * 2)),
                16, 0, 0);
        }
#pragma unroll
        for (int p = 0; p < 2; ++p) {
            int base_row = p * 32 + w * 8;
            int row = base_row + row8;
            const unsigned short* gp =
                Bt + (size_t)(bn + row) * K + k0 + ((slot ^ (row & 7)) * 8);
            __builtin_amdgcn_global_load_lds(
                (const __attribute__((address_space(1))) void*)gp,
                (__attribute__((address_space(3))) void*)(Bsl + base_row * (BK * 2)),
                16, 0, 0);
        }
    };

    int nt = K >> 6;
    stage(0, 0);
    __syncthreads();

    int cur = 0;
    for (int t = 0; t < nt; ++t) {
        if (t + 1 < nt) stage(cur ^ 1, (t + 1) * BK);

        char* Asl = lds[cur];
        char* Bsl = lds[cur] + BM * BK * 2;
#pragma unroll
        for (int kk = 0; kk < 2; ++kk) {
            int kb = kk * 64 + g * 16;
            s16x8 af[2], bfr[4];
#pragma unroll
            for (int mf = 0; mf < 2; ++mf) {
                int m = w * 32 + mf * 16 + r;
                int byte = (m * (BK * 2) + kb) ^ ((m & 7) << 4);
                af[mf] = *(const s16x8*)(Asl + byte);
            }
#pragma unroll
            for (int nf = 0; nf < 4; ++nf) {
                int n = nf * 16 + r;
                int byte = (n * (BK * 2) + kb) ^ ((n & 7) << 4);
                bfr[nf] = *(const s16x8*)(Bsl + byte);
            }
#pragma unroll
            for (int mf = 0; mf < 2; ++mf)
#pragma unroll
                for (int nf = 0; nf < 4; ++nf)
                    acc[mf][nf] = __builtin_amdgcn_mfma_f32_16x16x32_bf16(
                        af[mf], bfr[nf], acc[mf][nf], 0, 0, 0);
        }
        __syncthreads();
        cur ^= 1;
    }

    // C store
#pragma unroll
    for (int mf = 0; mf < 2; ++mf) {
#pragma unroll
        for (int nf = 0; nf < 4; ++nf) {
#pragma unroll
            for (int j = 0; j < 4; ++j) {
                int grow = bm + w * 32 + mf * 16 + g * 4 + j;
                if (grow < M)
                    Cbf[(size_t)grow * N + bn + nf * 16 + r] = f2bf(acc[mf][nf][j]);
            }
        }
    }

    // fused alpha: per-row partial dots with a_src/a_dst (this block's head)
    int hh = bn >> 7;          // C=128; BN=64 keeps a block within one head
    int cb = bn & 127;
    float a1v[4], a2v[4];
#pragma unroll
    for (int nf = 0; nf < 4; ++nf) {
        int ch = cb + nf * 16 + r;
        a1v[nf] = a_src[hh * 128 + ch];
        a2v[nf] = a_dst[hh * 128 + ch];
    }
#pragma unroll
    for (int mf = 0; mf < 2; ++mf) {
#pragma unroll
        for (int j = 0; j < 4; ++j) {
            float p1 = 0.f, p2 = 0.f;
#pragma unroll
            for (int nf = 0; nf < 4; ++nf) {
                p1 = fmaf(acc[mf][nf][j], a1v[nf], p1);
                p2 = fmaf(acc[mf][nf][j], a2v[nf], p2);
            }
#pragma unroll
            for (int off = 1; off < 16; off <<= 1) {
                p1 += __shfl_xor(p1, off);
                p2 += __shfl_xor(p2, off);
            }
            int grow = bm + w * 32 + mf * 16 + g * 4 + j;
            if (r == 0 && grow < M) {
                atomicAdd(&as_[(size_t)grow * H + hh], p1);
                atomicAdd(&ad_[(size_t)grow * H + hh], p2);
            }
        }
    }
}

// ---------------- 2-waves-per-node fused softmax + aggregation -------------
// Block = 256 thr = 2 nodes x 2 waves. Each wave owns half the node's edge
// range (own exs/ssh chunks, partial acc/den); combine once via LDS+sync.
// Single-pass unnormalized softmax: exp(lg) directly (logits bounded ~12,
// clamp 60 guards inf), normalize by summed den at the end.

template <int H, int C, bool DO_ELU, bool OUT_BF>
__global__ __launch_bounds__(256) void k_aggwave2(
    const unsigned short* __restrict__ hbf, const float* __restrict__ as_,
    const float* __restrict__ ad_, const int* __restrict__ row_ptr,
    const int* __restrict__ csr_src, const float* __restrict__ bias,
    float* __restrict__ outf, unsigned short* __restrict__ outb, int N) {
    constexpr int HC = H * C;
    constexpr int VEC = HC / 64;

    __shared__ float exs[4][H][72];     // per-wave; stride 72 = conflict-free
    __shared__ int ssh[4][64];
    __shared__ float pacc[2][VEC][64];  // odd-wave partial acc per node slot
    __shared__ float pden[2][H];

    int wv = threadIdx.x >> 6;     // 0..3
    int slotn = wv >> 1;           // node slot 0..1
    int half = wv & 1;             // which half of the edge range
    int n = blockIdx.x * 2 + slotn;
    bool valid = n < N;
    if (!valid) n = N - 1;         // clamp; duplicate work is benign
    int l = threadIdx.x & 63;
    int hh = (l * VEC) / C;
    int beg = row_ptr[n], end = row_ptr[n + 1];
    int deg = end - beg;
    int h0 = (deg + 1) >> 1;
    int mybeg = beg + half * h0;
    int myend = half ? end : (beg + h0);

    float adl[H];
#pragma unroll
    for (int q = 0; q < H; ++q) adl[q] = ad_[(size_t)n * H + q];

    float den[H];
#pragma unroll
    for (int q = 0; q < H; ++q) den[q] = 0.f;
    float acc[VEC];
#pragma unroll
    for (int k = 0; k < VEC; ++k) acc[k] = 0.f;

    const unsigned short* hb = hbf + (size_t)l * VEC;

    for (int c0 = mybeg; c0 < myend; c0 += 64) {
        int cn = myend - c0;
        if (cn > 64) cn = 64;
        if (l < cn) {
            int s = csr_src[c0 + l];
            ssh[wv][l] = s;
#pragma unroll
            for (int q = 0; q < H; ++q) {
                float lg = as_[(size_t)s * H + q] + adl[q];
                lg = (lg > 0.f) ? lg : NEG_SLOPE * lg;
                float ex = __expf(fminf(lg, 60.f));
                exs[wv][q][l] = ex;
                den[q] += ex;
            }
        }
        __builtin_amdgcn_wave_barrier();   // intra-wave fence (lockstep wave)

        constexpr int U = 8;
        int j = 0;
        for (; j + U <= cn; j += U) {
            int ss[U];
            float wg[U];
#pragma unroll
            for (int i = 0; i < U; ++i) {
                ss[i] = ssh[wv][j + i];
                wg[i] = exs[wv][hh][j + i];
            }
            if (VEC == 8) {
                s16x8 v[U];
#pragma unroll
                for (int i = 0; i < U; ++i)
                    v[i] = *(const s16x8*)(hb + (size_t)ss[i] * HC);
#pragma unroll
                for (int i = 0; i < U; ++i)
#pragma unroll
                    for (int k = 0; k < 8; ++k)
                        acc[k] = fmaf(wg[i], bf2f((unsigned short)v[i][k]), acc[k]);
            } else {
                unsigned int u[U];
#pragma unroll
                for (int i = 0; i < U; ++i)
                    u[i] = *(const unsigned int*)(hb + (size_t)ss[i] * HC);
#pragma unroll
                for (int i = 0; i < U; ++i) {
                    acc[0] = fmaf(wg[i], __builtin_bit_cast(float, u[i] << 16), acc[0]);
                    acc[1] = fmaf(wg[i], __builtin_bit_cast(float, u[i] & 0xffff0000u), acc[1]);
                }
            }
        }
        for (; j < cn; ++j) {
            int s = ssh[wv][j];
            float wg = exs[wv][hh][j];
            const unsigned short* hp = hb + (size_t)s * HC;
            if (VEC == 8) {
                s16x8 v = *(const s16x8*)hp;
#pragma unroll
                for (int k = 0; k < 8; ++k)
                    acc[k] = fmaf(wg, bf2f((unsigned short)v[k]), acc[k]);
            } else {
                unsigned int u = *(const unsigned int*)hp;
                acc[0] = fmaf(wg, __builtin_bit_cast(float, u << 16), acc[0]);
                acc[1] = fmaf(wg, __builtin_bit_cast(float, u & 0xffff0000u), acc[1]);
            }
        }
        __builtin_amdgcn_wave_barrier();
    }

    // per-wave den reduce
#pragma unroll
    for (int off = 32; off > 0; off >>= 1) {
#pragma unroll
        for (int q = 0; q < H; ++q) den[q] += __shfl_xor(den[q], off);
    }

    // cross-wave combine (odd wave publishes partials)
    if (half) {
#pragma unroll
        for (int k = 0; k < VEC; ++k) pacc[slotn][k][l] = acc[k];
        if (l < H) pden[slotn][l] = den[l];
    }
    __syncthreads();
    if (!half) {
#pragma unroll
        for (int k = 0; k < VEC; ++k) acc[k] += pacc[slotn][k][l];
#pragma unroll
        for (int q = 0; q < H; ++q) den[q] += pden[slotn][q];
        float rden = 1.f / (den[hh] + 1e-16f);
        if (valid) {
#pragma unroll
            for (int k = 0; k < VEC; ++k) {
                int ch = l * VEC + k;
                float v = fmaf(acc[k], rden, bias[ch]);
                if (DO_ELU) v = (v > 0.f) ? v : (__expf(v) - 1.f);
                if (OUT_BF)
                    outb[(size_t)n * HC + ch] = f2bf(v);
                else
                    outf[(size_t)n * HC + ch] = v;
            }
        }
    }
}

// ---------------------------------------------------------------------------

extern "C" void kernel_launch(void* const* d_in, const int* in_sizes, int n_in,
                              void* d_out, int out_size, void* d_ws, size_t ws_size,
                              hipStream_t stream) {
    const float* x = (const float*)d_in[0];
    const int* ei = (const int*)d_in[1];
    const float* W0 = (const float*)d_in[2];
    const float* as0 = (const float*)d_in[3];
    const float* ad0 = (const float*)d_in[4];
    const float* b0 = (const float*)d_in[5];
    const float* W1 = (const float*)d_in[6];
    const float* as1 = (const float*)d_in[7];
    const float* ad1 = (const float*)d_in[8];
    const float* b1 = (const float*)d_in[9];
    const float* W2 = (const float*)d_in[10];
    const float* as2 = (const float*)d_in[11];
    const float* ad2 = (const float*)d_in[12];
    const float* b2 = (const float*)d_in[13];

    const int N = in_sizes[0] / 256;   // 10000
    const int E = in_sizes[1] / 2;     // 320000
    const int Etot = E + N;
    const int IN_CH = 256, HEADS = 4, OUT_CH = 128;
    const int HC = HEADS * 128;        // 512

    // workspace layout
    float* ws = (float*)d_ws;
    float* as_ = ws;                        // N*4
    float* ad_ = as_ + (size_t)N * HEADS;   // N*4
    int* row_ptr = (int*)(ad_ + (size_t)N * HEADS);  // N+1
    int* cursor = row_ptr + (N + 1);        // N
    int* counts = cursor + N;               // N
    int* csr_src = counts + N;              // Etot
    uintptr_t p = (uintptr_t)(csr_src + Etot);
    p = (p + 15) & ~(uintptr_t)15;
    unsigned short* abf = (unsigned short*)p;        // N*512 bf16 (GEMM A / agg out)
    unsigned short* hbf = abf + (size_t)N * HC;      // N*512 bf16 (GEMM out)
    unsigned short* wt0 = hbf + (size_t)N * HC;      // 512*256
    unsigned short* wt1 = wt0 + (size_t)HC * IN_CH;  // 512*512
    unsigned short* wt2 = wt1 + (size_t)HC * HC;     // 128*512

    // ---- prep: counts zero + as_/ad_ zero + fused prep + CSR ----
    hipMemsetAsync(counts, 0, (size_t)N * sizeof(int), stream);
    hipMemsetAsync(as_, 0, (size_t)2 * N * HEADS * sizeof(float), stream);
    int eb = (Etot + 255) / 256;
    int nx = N * IN_CH;
    int ab = (nx / 4 + 255) / 256;
    k_prep<<<eb + 448 + ab, 256, 0, stream>>>(ei, E, N, counts, W0, wt0, W1, wt1,
                                              W2, wt2, x, abf, nx, eb);
    k_scan<<<1, 256, 0, stream>>>(counts, N, row_ptr, cursor);
    k_fill<<<(Etot + 255) / 256, 256, 0, stream>>>(ei, E, N, cursor, csr_src);

    int aggblocks = (N + 1) / 2;

    // ---- layer 0: x[N,256] @ W0[256,512] ----
    {
        dim3 grid((N + 127) / 128, HC / 64);
        k_mgemm<<<grid, 256, 0, stream>>>(abf, wt0, hbf, as0, ad0, as_, ad_,
                                          N, HC, IN_CH, HEADS);
        k_aggwave2<4, 128, true, true><<<aggblocks, 256, 0, stream>>>(
            hbf, as_, ad_, row_ptr, csr_src, b0, nullptr, abf, N);
    }
    // ---- layer 1: abf[N,512] @ W1[512,512] ----
    {
        hipMemsetAsync(as_, 0, (size_t)2 * N * HEADS * sizeof(float), stream);
        dim3 grid((N + 127) / 128, HC / 64);
        k_mgemm<<<grid, 256, 0, stream>>>(abf, wt1, hbf, as1, ad1, as_, ad_,
                                          N, HC, HC, HEADS);
        k_aggwave2<4, 128, true, true><<<aggblocks, 256, 0, stream>>>(
            hbf, as_, ad_, row_ptr, csr_src, b1, nullptr, abf, N);
    }
    // ---- layer 2: abf[N,512] @ W2[512,128], heads=1, no ELU ----
    {
        hipMemsetAsync(as_, 0, (size_t)2 * N * HEADS * sizeof(float), stream);
        dim3 grid((N + 127) / 128, OUT_CH / 64);
        k_mgemm<<<grid, 256, 0, stream>>>(abf, wt2, hbf, as2, ad2, as_, ad_,
                                          N, OUT_CH, HC, 1);
        k_aggwave2<1, 128, false, false><<<aggblocks, 256, 0, stream>>>(
            hbf, as_, ad_, row_ptr, csr_src, b2, (float*)d_out, nullptr, N);
    }
}

// Round 10
// 282.446 us; speedup vs baseline: 1.1278x; 1.1278x over previous
//
#include <hip/hip_runtime.h>
#include <math.h>

// ---------------------------------------------------------------------------
// GAT 3-layer forward. GEMMs bf16-MFMA (f32 acc, global_load_lds dbuf) with
// fused alpha-dot epilogue; aggregation = per-(node,head) wave passes so each
// XCD's gather working set is one 2.5MB head-slice (L2-resident), head pinned
// to XCD via blockIdx&3. Single-pass unnormalized softmax (logits ~12 << 88).
// N=10000, IN=256, HID=128, HEADS=4, OUT=128, E=320000 (+N self loops).
// ---------------------------------------------------------------------------

#define NEG_SLOPE 0.2f

typedef float f32x4 __attribute__((ext_vector_type(4)));
typedef short s16x8 __attribute__((ext_vector_type(8)));

__device__ inline unsigned short f2bf(float x) {
    unsigned int u = __builtin_bit_cast(unsigned int, x);
    u = (u + 0x7fff + ((u >> 16) & 1)) >> 16;   // RNE
    return (unsigned short)u;
}
__device__ inline float bf2f(unsigned short b) {
    return __builtin_bit_cast(float, ((unsigned int)b) << 16);
}

// ---------------- CSR build (scan + fill) ----------------

__global__ __launch_bounds__(1024) void k_scan(const int* __restrict__ counts, int N,
                                               int* __restrict__ row_ptr,
                                               int* __restrict__ cursor) {
    __shared__ int s[1024];
    int t = threadIdx.x;
    int per = (N + 1023) / 1024;
    int beg = t * per;
    int local = 0;
    for (int j = 0; j < per; ++j) {
        int i = beg + j;
        if (i < N) local += counts[i];
    }
    s[t] = local;
    __syncthreads();
    for (int off = 1; off < 1024; off <<= 1) {
        int v = (t >= off) ? s[t - off] : 0;
        __syncthreads();
        s[t] += v;
        __syncthreads();
    }
    int run = (t == 0) ? 0 : s[t - 1];
    for (int j = 0; j < per; ++j) {
        int i = beg + j;
        if (i < N) {
            row_ptr[i] = run;
            cursor[i] = run;
            run += counts[i];
        }
    }
    if (t == 1023) row_ptr[N] = s[1023];
}

__global__ void k_fill(const int* __restrict__ ei, int E, int N,
                       int* __restrict__ cursor, int* __restrict__ csr_src) {
    int e = blockIdx.x * blockDim.x + threadIdx.x;
    if (e >= E + N) return;
    int src, dst;
    if (e < E) {
        src = ei[e];
        dst = ei[(size_t)E + e];
    } else {
        src = dst = e - E;
    }
    if ((unsigned)dst >= (unsigned)N || (unsigned)src >= (unsigned)N) return;
    int slot = atomicAdd(&cursor[dst], 1);
    csr_src[slot] = src;
}

// ---------------- fused prep: edge-count | weight transpose-cast | x cast ---

__global__ __launch_bounds__(256) void k_prep(
    const int* __restrict__ ei, int E, int N, int* __restrict__ counts,
    const float* __restrict__ W0c, unsigned short* __restrict__ T0,
    const float* __restrict__ W1c, unsigned short* __restrict__ T1,
    const float* __restrict__ W2c, unsigned short* __restrict__ T2,
    const float* __restrict__ x, unsigned short* __restrict__ xo, int nx, int eb) {
    __shared__ float tile[32][33];
    int bid = blockIdx.x;
    if (bid < eb) {
        int e = bid * 256 + threadIdx.x;
        if (e >= E + N) return;
        int dst = (e < E) ? ei[(size_t)E + e] : (e - E);
        if ((unsigned)dst >= (unsigned)N) return;
        atomicAdd(&counts[dst], 1);
        return;
    }
    bid -= eb;
    if (bid < 448) {
        const float* W;
        unsigned short* T;
        int K, Nc, t;
        if (bid < 128)      { W = W0c; T = T0; K = 256; Nc = 512; t = bid; }
        else if (bid < 384) { W = W1c; T = T1; K = 512; Nc = 512; t = bid - 128; }
        else                { W = W2c; T = T2; K = 512; Nc = 128; t = bid - 384; }
        int nt = Nc / 32;
        int n0 = (t % nt) * 32, k0 = (t / nt) * 32;
        int tx = threadIdx.x % 32, ty = threadIdx.x / 32;  // 32 x 8
#pragma unroll
        for (int i = 0; i < 32; i += 8)
            tile[ty + i][tx] = W[(size_t)(k0 + ty + i) * Nc + n0 + tx];
        __syncthreads();
#pragma unroll
        for (int i = 0; i < 32; i += 8)
            T[(size_t)(n0 + ty + i) * K + k0 + tx] = f2bf(tile[tx][ty + i]);
        return;
    }
    bid -= 448;
    int i = (bid * 256 + threadIdx.x) * 4;
    if (i >= nx) return;
    if (i + 3 >= nx) {
        for (int j = i; j < nx; ++j) xo[j] = f2bf(x[j]);
        return;
    }
    float4 v = *(const float4*)(x + i);
    xo[i + 0] = f2bf(v.x);
    xo[i + 1] = f2bf(v.y);
    xo[i + 2] = f2bf(v.z);
    xo[i + 3] = f2bf(v.w);
}

// ---------------- bf16 MFMA GEMM + fused alpha-dot epilogue ----------------
// Cbf[M][N] = A[M][K](bf16) * Bt[N][K]^T(bf16).  BM=128 BN=64 BK=64, 4 waves.
// Epilogue accumulates as_[m,h]=<C[m,:],a_src[h,:]> (and ad_) via one f32
// atomicAdd per row per block (a block's columns lie within ONE head).

__global__ __launch_bounds__(256) void k_mgemm(const unsigned short* __restrict__ A,
                                               const unsigned short* __restrict__ Bt,
                                               unsigned short* __restrict__ Cbf,
                                               const float* __restrict__ a_src,
                                               const float* __restrict__ a_dst,
                                               float* __restrict__ as_,
                                               float* __restrict__ ad_,
                                               int M, int N, int K, int H) {
    constexpr int BM = 128, BN = 64, BK = 64;
    constexpr int BUF = (BM + BN) * BK * 2;      // 24576 bytes
    __shared__ char lds[2][BUF];

    int tid = threadIdx.x;
    int w = tid >> 6, l = tid & 63;
    int r = l & 15, g = l >> 4;
    int bm = blockIdx.x * BM, bn = blockIdx.y * BN;

    int row8 = l >> 3;
    int slot = l & 7;

    f32x4 acc[2][4];
#pragma unroll
    for (int i = 0; i < 2; ++i)
#pragma unroll
        for (int j = 0; j < 4; ++j) acc[i][j] = (f32x4)0.f;

    auto stage = [&](int buf, int k0) {
        char* Asl = lds[buf];
        char* Bsl = lds[buf] + BM * BK * 2;
#pragma unroll
        for (int p = 0; p < 4; ++p) {
            int base_row = p * 32 + w * 8;
            int row = base_row + row8;
            const unsigned short* gp =
                A + (size_t)(bm + row) * K + k0 + ((slot ^ (row & 7)) * 8);
            __builtin_amdgcn_global_load_lds(
                (const __attribute__((address_space(1))) void*)gp,
                (__attribute__((address_space(3))) void*)(Asl + base_row * (BK * 2)),
                16, 0, 0);
        }
#pragma unroll
        for (int p = 0; p < 2; ++p) {
            int base_row = p * 32 + w * 8;
            int row = base_row + row8;
            const unsigned short* gp =
                Bt + (size_t)(bn + row) * K + k0 + ((slot ^ (row & 7)) * 8);
            __builtin_amdgcn_global_load_lds(
                (const __attribute__((address_space(1))) void*)gp,
                (__attribute__((address_space(3))) void*)(Bsl + base_row * (BK * 2)),
                16, 0, 0);
        }
    };

    int nt = K >> 6;
    stage(0, 0);
    __syncthreads();

    int cur = 0;
    for (int t = 0; t < nt; ++t) {
        if (t + 1 < nt) stage(cur ^ 1, (t + 1) * BK);

        char* Asl = lds[cur];
        char* Bsl = lds[cur] + BM * BK * 2;
#pragma unroll
        for (int kk = 0; kk < 2; ++kk) {
            int kb = kk * 64 + g * 16;
            s16x8 af[2], bfr[4];
#pragma unroll
            for (int mf = 0; mf < 2; ++mf) {
                int m = w * 32 + mf * 16 + r;
                int byte = (m * (BK * 2) + kb) ^ ((m & 7) << 4);
                af[mf] = *(const s16x8*)(Asl + byte);
            }
#pragma unroll
            for (int nf = 0; nf < 4; ++nf) {
                int n = nf * 16 + r;
                int byte = (n * (BK * 2) + kb) ^ ((n & 7) << 4);
                bfr[nf] = *(const s16x8*)(Bsl + byte);
            }
#pragma unroll
            for (int mf = 0; mf < 2; ++mf)
#pragma unroll
                for (int nf = 0; nf < 4; ++nf)
                    acc[mf][nf] = __builtin_amdgcn_mfma_f32_16x16x32_bf16(
                        af[mf], bfr[nf], acc[mf][nf], 0, 0, 0);
        }
        __syncthreads();
        cur ^= 1;
    }

    // C store
#pragma unroll
    for (int mf = 0; mf < 2; ++mf) {
#pragma unroll
        for (int nf = 0; nf < 4; ++nf) {
#pragma unroll
            for (int j = 0; j < 4; ++j) {
                int grow = bm + w * 32 + mf * 16 + g * 4 + j;
                if (grow < M)
                    Cbf[(size_t)grow * N + bn + nf * 16 + r] = f2bf(acc[mf][nf][j]);
            }
        }
    }

    // fused alpha: per-row partial dots with a_src/a_dst (this block's head)
    int hh = bn >> 7;          // C=128; BN=64 keeps a block within one head
    int cb = bn & 127;
    float a1v[4], a2v[4];
#pragma unroll
    for (int nf = 0; nf < 4; ++nf) {
        int ch = cb + nf * 16 + r;
        a1v[nf] = a_src[hh * 128 + ch];
        a2v[nf] = a_dst[hh * 128 + ch];
    }
#pragma unroll
    for (int mf = 0; mf < 2; ++mf) {
#pragma unroll
        for (int j = 0; j < 4; ++j) {
            float p1 = 0.f, p2 = 0.f;
#pragma unroll
            for (int nf = 0; nf < 4; ++nf) {
                p1 = fmaf(acc[mf][nf][j], a1v[nf], p1);
                p2 = fmaf(acc[mf][nf][j], a2v[nf], p2);
            }
#pragma unroll
            for (int off = 1; off < 16; off <<= 1) {
                p1 += __shfl_xor(p1, off);
                p2 += __shfl_xor(p2, off);
            }
            int grow = bm + w * 32 + mf * 16 + g * 4 + j;
            if (r == 0 && grow < M) {
                atomicAdd(&as_[(size_t)grow * H + hh], p1);
                atomicAdd(&ad_[(size_t)grow * H + hh], p2);
            }
        }
    }
}

// ---------------- per-(node,head) fused softmax + aggregation --------------
// Wave = 4 edge-slots x 16 lanes; each lane reads 16B of the 256B head-slice.
// head = blockIdx&3 pins each XCD (blockIdx%8 round-robin) to ONE 2.5MB
// h-slice -> L2-resident gather. Unnormalized single-pass softmax
// (exp(min(lg,60)) directly; logits bounded ~12), normalize by den at end.

template <int H, bool DO_ELU, bool OUT_BF>
__global__ __launch_bounds__(256) void k_agghead(
    const unsigned short* __restrict__ hbf, const float* __restrict__ as_,
    const float* __restrict__ ad_, const int* __restrict__ row_ptr,
    const int* __restrict__ csr_src, const float* __restrict__ bias,
    float* __restrict__ outf, unsigned short* __restrict__ outb, int N) {
    constexpr int HC = H * 128;
    int bid = blockIdx.x;
    int q, grp;
    if (H == 4) { q = bid & 3; grp = bid >> 2; }   // XCD x -> head x&3 only
    else        { q = 0; grp = bid; }
    int wv = threadIdx.x >> 6;
    int n = grp * 4 + wv;
    if (n >= N) return;
    int l = threadIdx.x & 63;
    int eg = l >> 4;      // edge slot 0..3
    int r = l & 15;       // 16B lane-slot within 256B row slice
    int beg = row_ptr[n], end = row_ptr[n + 1];
    float adq = ad_[(size_t)n * H + q];

    float den = 0.f;
    float acc[8];
#pragma unroll
    for (int k = 0; k < 8; ++k) acc[k] = 0.f;

    const unsigned short* hq = hbf + q * 128 + r * 8;

    for (int e0 = beg; e0 < end; e0 += 16) {
        int s[4];
        float msk[4];
#pragma unroll
        for (int u = 0; u < 4; ++u) {
            int e = e0 + u * 4 + eg;
            s[u] = csr_src[e < end ? e : end - 1];
            msk[u] = (e < end) ? 1.f : 0.f;
        }
        s16x8 v[4];
#pragma unroll
        for (int u = 0; u < 4; ++u)
            v[u] = *(const s16x8*)(hq + (size_t)s[u] * HC);
        float wg[4];
#pragma unroll
        for (int u = 0; u < 4; ++u) {
            float lg = as_[(size_t)s[u] * H + q] + adq;
            lg = (lg > 0.f) ? lg : NEG_SLOPE * lg;
            float ex = __expf(fminf(lg, 60.f)) * msk[u];
            den += ex;
            wg[u] = ex;
        }
#pragma unroll
        for (int u = 0; u < 4; ++u)
#pragma unroll
            for (int k = 0; k < 8; ++k)
                acc[k] = fmaf(wg[u], bf2f((unsigned short)v[u][k]), acc[k]);
    }

    // reduce across the 4 edge-slot groups (lane^16, lane^32)
#pragma unroll
    for (int k = 0; k < 8; ++k) {
        acc[k] += __shfl_xor(acc[k], 16);
        acc[k] += __shfl_xor(acc[k], 32);
    }
    den += __shfl_xor(den, 16);
    den += __shfl_xor(den, 32);

    if (eg == 0) {
        float rden = 1.f / (den + 1e-16f);
        int chb = q * 128 + r * 8;
        if (OUT_BF) {
            s16x8 o;
#pragma unroll
            for (int k = 0; k < 8; ++k) {
                float vv = fmaf(acc[k], rden, bias[chb + k]);
                if (DO_ELU) vv = (vv > 0.f) ? vv : (__expf(vv) - 1.f);
                o[k] = (short)f2bf(vv);
            }
            *(s16x8*)(outb + (size_t)n * HC + chb) = o;
        } else {
            f32x4 o0, o1;
#pragma unroll
            for (int k = 0; k < 8; ++k) {
                float vv = fmaf(acc[k], rden, bias[chb + k]);
                if (DO_ELU) vv = (vv > 0.f) ? vv : (__expf(vv) - 1.f);
                if (k < 4) o0[k] = vv; else o1[k - 4] = vv;
            }
            *(f32x4*)(outf + (size_t)n * HC + chb) = o0;
            *(f32x4*)(outf + (size_t)n * HC + chb + 4) = o1;
        }
    }
}

// ---------------------------------------------------------------------------

extern "C" void kernel_launch(void* const* d_in, const int* in_sizes, int n_in,
                              void* d_out, int out_size, void* d_ws, size_t ws_size,
                              hipStream_t stream) {
    const float* x = (const float*)d_in[0];
    const int* ei = (const int*)d_in[1];
    const float* W0 = (const float*)d_in[2];
    const float* as0 = (const float*)d_in[3];
    const float* ad0 = (const float*)d_in[4];
    const float* b0 = (const float*)d_in[5];
    const float* W1 = (const float*)d_in[6];
    const float* as1 = (const float*)d_in[7];
    const float* ad1 = (const float*)d_in[8];
    const float* b1 = (const float*)d_in[9];
    const float* W2 = (const float*)d_in[10];
    const float* as2 = (const float*)d_in[11];
    const float* ad2 = (const float*)d_in[12];
    const float* b2 = (const float*)d_in[13];

    const int N = in_sizes[0] / 256;   // 10000
    const int E = in_sizes[1] / 2;     // 320000
    const int Etot = E + N;
    const int IN_CH = 256, HEADS = 4, OUT_CH = 128;
    const int HC = HEADS * 128;        // 512

    // workspace layout: [counts N][alpha 18N f32][row_ptr N+1][cursor N][csr Etot][bf16...]
    int* counts = (int*)d_ws;
    float* alpha = (float*)(counts + N);
    float* A0s = alpha;                 // 4N
    float* A0d = alpha + 4 * (size_t)N; // 4N
    float* A1s = alpha + 8 * (size_t)N;
    float* A1d = alpha + 12 * (size_t)N;
    float* A2s = alpha + 16 * (size_t)N;  // N
    float* A2d = alpha + 17 * (size_t)N;  // N
    int* row_ptr = (int*)(alpha + 18 * (size_t)N);  // N+1
    int* cursor = row_ptr + (N + 1);
    int* csr_src = cursor + N;          // Etot
    uintptr_t p = (uintptr_t)(csr_src + Etot);
    p = (p + 15) & ~(uintptr_t)15;
    unsigned short* abf = (unsigned short*)p;        // N*512 bf16 (GEMM A / agg out)
    unsigned short* hbf = abf + (size_t)N * HC;      // N*512 bf16 (GEMM out)
    unsigned short* wt0 = hbf + (size_t)N * HC;      // 512*256
    unsigned short* wt1 = wt0 + (size_t)HC * IN_CH;  // 512*512
    unsigned short* wt2 = wt1 + (size_t)HC * HC;     // 128*512

    // ---- one upfront zero of counts + all alpha buffers, then prep + CSR ----
    hipMemsetAsync(counts, 0, (size_t)(N + 18 * (size_t)N) * sizeof(int), stream);
    int eb = (Etot + 255) / 256;
    int nx = N * IN_CH;
    int ab = (nx / 4 + 255) / 256;
    k_prep<<<eb + 448 + ab, 256, 0, stream>>>(ei, E, N, counts, W0, wt0, W1, wt1,
                                              W2, wt2, x, abf, nx, eb);
    k_scan<<<1, 1024, 0, stream>>>(counts, N, row_ptr, cursor);
    k_fill<<<(Etot + 255) / 256, 256, 0, stream>>>(ei, E, N, cursor, csr_src);

    // ---- layer 0: x[N,256] @ W0[256,512] ----
    {
        dim3 grid((N + 127) / 128, HC / 64);
        k_mgemm<<<grid, 256, 0, stream>>>(abf, wt0, hbf, as0, ad0, A0s, A0d,
                                          N, HC, IN_CH, HEADS);
        k_agghead<4, true, true><<<N, 256, 0, stream>>>(
            hbf, A0s, A0d, row_ptr, csr_src, b0, nullptr, abf, N);
    }
    // ---- layer 1: abf[N,512] @ W1[512,512] ----
    {
        dim3 grid((N + 127) / 128, HC / 64);
        k_mgemm<<<grid, 256, 0, stream>>>(abf, wt1, hbf, as1, ad1, A1s, A1d,
                                          N, HC, HC, HEADS);
        k_agghead<4, true, true><<<N, 256, 0, stream>>>(
            hbf, A1s, A1d, row_ptr, csr_src, b1, nullptr, abf, N);
    }
    // ---- layer 2: abf[N,512] @ W2[512,128], heads=1, no ELU ----
    {
        dim3 grid((N + 127) / 128, OUT_CH / 64);
        k_mgemm<<<grid, 256, 0, stream>>>(abf, wt2, hbf, as2, ad2, A2s, A2d,
                                          N, OUT_CH, HC, 1);
        k_agghead<1, false, false><<<(N + 3) / 4, 256, 0, stream>>>(
            hbf, A2s, A2d, row_ptr, csr_src, b2, (float*)d_out, nullptr, N);
    }
}